// Round 1
// baseline (2016.440 us; speedup 1.0000x reference)
//
#include <hip/hip_runtime.h>
#include <hip/hip_bf16.h>

// Problem constants (match reference globals)
#define S_TOT 5440
#define C_DIM 256
#define F_DIM 1024
#define N_LAYERS 6

__device__ __constant__ int c_HW[4]     = {64, 32, 16, 8};
__device__ __constant__ int c_start[4]  = {0, 4096, 5120, 5376};

// ---------------- Tiled fp32 GEMM: C = (A [+A2]) @ W + bias [+res] [relu] ----------------
// A: M x K row-major, W: K x N row-major. M%64==0, N%64==0, K%16==0 assumed.
__global__ __launch_bounds__(256) void gemm_f32(
    const float* __restrict__ A, const float* __restrict__ A2,
    const float* __restrict__ W, const float* __restrict__ bias,
    const float* __restrict__ res, float* __restrict__ C,
    int M, int K, int N, int relu)
{
    __shared__ float As[16][68];   // [k][m], padded stride 68 (272B, 16B-aligned rows)
    __shared__ float Ws[16][64];   // [k][n]

    const int t  = threadIdx.x;
    const int tx = t & 15;         // output col group
    const int ty = t >> 4;         // output row group
    const int mBase = blockIdx.x * 64;
    const int nBase = blockIdx.y * 64;

    const int aRow = t >> 4;       // 0..15
    const int aCol = t & 15;       // 0..15
    const int wCol = t & 63;       // 0..63
    const int wRow = t >> 6;       // 0..3

    float acc[4][4] = {};

    for (int k0 = 0; k0 < K; k0 += 16) {
        // Load A tile (64 x 16)
        #pragma unroll
        for (int i = 0; i < 4; ++i) {
            int r  = aRow + i * 16;
            int gr = mBase + r;
            float v = A[(long)gr * K + k0 + aCol];
            if (A2) v += A2[(long)gr * K + k0 + aCol];
            As[aCol][r] = v;
        }
        // Load W tile (16 x 64)
        #pragma unroll
        for (int i = 0; i < 4; ++i) {
            int r = wRow + i * 4;
            Ws[r][wCol] = W[(long)(k0 + r) * N + nBase + wCol];
        }
        __syncthreads();
        #pragma unroll
        for (int kk = 0; kk < 16; ++kk) {
            float a[4], w[4];
            #pragma unroll
            for (int j = 0; j < 4; ++j) a[j] = As[kk][ty * 4 + j];
            #pragma unroll
            for (int j = 0; j < 4; ++j) w[j] = Ws[kk][tx * 4 + j];
            #pragma unroll
            for (int r = 0; r < 4; ++r)
                #pragma unroll
                for (int c = 0; c < 4; ++c)
                    acc[r][c] += a[r] * w[c];
        }
        __syncthreads();
    }

    #pragma unroll
    for (int r = 0; r < 4; ++r) {
        int gr = mBase + ty * 4 + r;
        #pragma unroll
        for (int c = 0; c < 4; ++c) {
            int gc = nBase + tx * 4 + c;
            float v = acc[r][c] + bias[gc];
            if (res)  v += res[(long)gr * N + gc];
            if (relu) v = fmaxf(v, 0.f);
            C[(long)gr * N + gc] = v;
        }
    }
}

// ---------------- MSDA sampling: one block per query ----------------
// value: S x 256 (S,8,32), offraw: S x 256 (S,8,4,4,2), logits: S x 128 (S,8,16)
// vr: (1,4,2) valid ratios. out: S x 256.
__global__ __launch_bounds__(256) void msda_sample(
    const float* __restrict__ value, const float* __restrict__ offraw,
    const float* __restrict__ logits, const float* __restrict__ vr,
    float* __restrict__ out)
{
    const int s = blockIdx.x;
    const int t = threadIdx.x;

    __shared__ float sOff[256];
    __shared__ float sAw[128];

    sOff[t] = offraw[(long)s * 256 + t];
    if (t < 128) sAw[t] = logits[(long)s * 128 + t];
    __syncthreads();

    if (t < 8) {  // per-head softmax over 16
        float m = -1e30f;
        #pragma unroll
        for (int i = 0; i < 16; ++i) m = fmaxf(m, sAw[t * 16 + i]);
        float sum = 0.f;
        #pragma unroll
        for (int i = 0; i < 16; ++i) { float e = expf(sAw[t * 16 + i] - m); sAw[t * 16 + i] = e; sum += e; }
        float inv = 1.f / sum;
        #pragma unroll
        for (int i = 0; i < 16; ++i) sAw[t * 16 + i] *= inv;
    }
    __syncthreads();

    // reference point for this query (levels are square: H==W)
    int ls = (s < 4096) ? 0 : (s < 5120) ? 1 : (s < 5376) ? 2 : 3;
    int Wq = c_HW[ls];
    int rem = s - c_start[ls];
    int qi = rem / Wq, qj = rem % Wq;
    float xh = (qj + 0.5f) / (vr[ls * 2 + 1] * (float)Wq);
    float yh = (qi + 0.5f) / (vr[ls * 2 + 0] * (float)Wq);

    const int h = t >> 5, d = t & 31;
    const float* voff = value + h * 32 + d;
    float acc = 0.f;

    #pragma unroll
    for (int l = 0; l < 4; ++l) {
        const int Wl = c_HW[l];
        const int sl = c_start[l];
        const float fW = (float)Wl;
        const float refx = xh * vr[l * 2 + 1];
        const float refy = yh * vr[l * 2 + 0];
        #pragma unroll
        for (int p = 0; p < 4; ++p) {
            const int oi = ((h * 4 + l) * 4 + p) * 2;
            float lx = refx + sOff[oi]     / fW;
            float ly = refy + sOff[oi + 1] / fW;   // H==W per level
            float x = lx * fW - 0.5f;
            float y = ly * fW - 0.5f;
            float x0f = floorf(x), y0f = floorf(y);
            float fx = x - x0f, fy = y - y0f;
            int x0 = (int)x0f, y0 = (int)y0f;
            float aw = sAw[h * 16 + l * 4 + p];

            float v00 = 0.f, v01 = 0.f, v10 = 0.f, v11 = 0.f;
            bool xin0 = (x0 >= 0) & (x0 < Wl);
            bool xin1 = (x0 + 1 >= 0) & (x0 + 1 < Wl);
            bool yin0 = (y0 >= 0) & (y0 < Wl);
            bool yin1 = (y0 + 1 >= 0) & (y0 + 1 < Wl);
            if (xin0 & yin0) v00 = voff[(long)(sl + y0 * Wl + x0) * 256];
            if (xin1 & yin0) v01 = voff[(long)(sl + y0 * Wl + x0 + 1) * 256];
            if (xin0 & yin1) v10 = voff[(long)(sl + (y0 + 1) * Wl + x0) * 256];
            if (xin1 & yin1) v11 = voff[(long)(sl + (y0 + 1) * Wl + x0 + 1) * 256];

            float bi = v00 * (1.f - fx) * (1.f - fy) + v01 * fx * (1.f - fy)
                     + v10 * (1.f - fx) * fy         + v11 * fx * fy;
            acc += aw * bi;
        }
    }
    out[(long)s * 256 + t] = acc;
}

// ---------------- LayerNorm over C=256, one block (256 thr) per row ----------------
__global__ __launch_bounds__(256) void ln_k(
    const float* __restrict__ in, const float* __restrict__ g,
    const float* __restrict__ b, float* __restrict__ out)
{
    const int s = blockIdx.x;
    const int t = threadIdx.x;
    float v = in[(long)s * 256 + t];

    __shared__ float red[4];
    __shared__ float red2[4];
    const int wid = t >> 6, lane = t & 63;

    float sum = v;
    #pragma unroll
    for (int o = 32; o > 0; o >>= 1) sum += __shfl_down(sum, o);
    if (lane == 0) red[wid] = sum;
    __syncthreads();
    if (t == 0) red[0] = (red[0] + red[1] + red[2] + red[3]) * (1.f / 256.f);
    __syncthreads();
    const float mean = red[0];

    float dv = v - mean;
    float sq = dv * dv;
    #pragma unroll
    for (int o = 32; o > 0; o >>= 1) sq += __shfl_down(sq, o);
    if (lane == 0) red2[wid] = sq;
    __syncthreads();
    if (t == 0) red2[0] = (red2[0] + red2[1] + red2[2] + red2[3]) * (1.f / 256.f);
    __syncthreads();
    const float var = red2[0];

    out[(long)s * 256 + t] = dv * rsqrtf(var + 1e-5f) * g[t] + b[t];
}

extern "C" void kernel_launch(void* const* d_in, const int* in_sizes, int n_in,
                              void* d_out, int out_size, void* d_ws, size_t ws_size,
                              hipStream_t stream) {
    const float* src   = (const float*)d_in[0];
    const float* pos   = (const float*)d_in[1];
    const float* vr    = (const float*)d_in[2];
    // d_in[3] spatial_shapes, d_in[4] level_start_index: hardcoded constants
    const float* Wv    = (const float*)d_in[5];
    const float* bv    = (const float*)d_in[6];
    const float* Woff  = (const float*)d_in[7];
    const float* boff  = (const float*)d_in[8];
    const float* Wattn = (const float*)d_in[9];
    const float* battn = (const float*)d_in[10];
    const float* Wout  = (const float*)d_in[11];
    const float* bout  = (const float*)d_in[12];
    const float* ln1g  = (const float*)d_in[13];
    const float* ln1b  = (const float*)d_in[14];
    const float* W1    = (const float*)d_in[15];
    const float* b1    = (const float*)d_in[16];
    const float* W2    = (const float*)d_in[17];
    const float* b2    = (const float*)d_in[18];
    const float* ln2g  = (const float*)d_in[19];
    const float* ln2b  = (const float*)d_in[20];

    const int S = S_TOT, C = C_DIM, F = F_DIM;
    const long SC = (long)S * C;

    float* ws     = (float*)d_ws;
    float* xbuf   = ws;                 // S*C
    float* value  = xbuf   + SC;        // S*C
    float* offraw = value  + SC;        // S*C
    float* logits = offraw + SC;        // S*128
    float* msda   = logits + (long)S * 128; // S*C
    float* tmp    = msda   + SC;        // S*C
    float* hbuf   = tmp    + SC;        // S*F

    const float* x = src;
    for (int i = 0; i < N_LAYERS; ++i) {
        const float* Wv_i = Wv + (long)i * C * C;
        const float* Wo_i = Woff + (long)i * C * 256;
        const float* Wa_i = Wattn + (long)i * C * 128;
        const float* Wu_i = Wout + (long)i * C * C;
        const float* W1_i = W1 + (long)i * C * F;
        const float* W2_i = W2 + (long)i * F * C;

        // value = x @ Wv + bv
        gemm_f32<<<dim3(85, 4), 256, 0, stream>>>(x, nullptr, Wv_i, bv + i * C, nullptr, value, S, C, C, 0);
        // offraw = (x+pos) @ Woff + boff
        gemm_f32<<<dim3(85, 4), 256, 0, stream>>>(x, pos, Wo_i, boff + i * 256, nullptr, offraw, S, C, 256, 0);
        // logits = (x+pos) @ Wattn + battn
        gemm_f32<<<dim3(85, 2), 256, 0, stream>>>(x, pos, Wa_i, battn + i * 128, nullptr, logits, S, C, 128, 0);
        // msda sampling
        msda_sample<<<S, 256, 0, stream>>>(value, offraw, logits, vr, msda);
        // tmp = msda @ Wout + bout + x
        gemm_f32<<<dim3(85, 4), 256, 0, stream>>>(msda, nullptr, Wu_i, bout + i * C, x, tmp, S, C, C, 0);
        // xbuf = LN1(tmp)
        ln_k<<<S, 256, 0, stream>>>(tmp, ln1g + i * C, ln1b + i * C, xbuf);
        // hbuf = relu(xbuf @ W1 + b1)
        gemm_f32<<<dim3(85, 16), 256, 0, stream>>>(xbuf, nullptr, W1_i, b1 + i * F, nullptr, hbuf, S, C, F, 1);
        // tmp = hbuf @ W2 + b2 + xbuf
        gemm_f32<<<dim3(85, 4), 256, 0, stream>>>(hbuf, nullptr, W2_i, b2 + i * C, xbuf, tmp, S, F, C, 0);
        // x = LN2(tmp)  (last layer -> d_out)
        float* dst = (i == N_LAYERS - 1) ? (float*)d_out : xbuf;
        ln_k<<<S, 256, 0, stream>>>(tmp, ln2g + i * C, ln2b + i * C, dst);
        x = xbuf;
    }
}

// Round 2
// 1010.117 us; speedup vs baseline: 1.9962x; 1.9962x over previous
//
#include <hip/hip_runtime.h>
#include <hip/hip_bf16.h>

#define S_TOT 5440
#define C_DIM 256
#define F_DIM 1024
#define N_LAYERS 6

__device__ __constant__ int c_HW[4]     = {64, 32, 16, 8};
__device__ __constant__ int c_start[4]  = {0, 4096, 5120, 5376};

typedef __attribute__((ext_vector_type(8))) short bf16x8;
typedef __attribute__((ext_vector_type(4))) float f32x4;

__device__ __forceinline__ short f2bf(float f) {
    __hip_bfloat16 h = __float2bfloat16(f);
    return *reinterpret_cast<short*>(&h);
}

// ============ bf16-MFMA GEMM core as a device function ============
// Computes a 64x64 output tile at (mBase, nBase) of (A[+A2]) @ W, A: MxK f32
// row-major, W: KxN f32 row-major, staging converts to bf16. acc returned.
// Each of 4 waves owns a 32x32 quadrant; 2x2 fragments of 16x16; BK=32.
struct TileCtx {
    f32x4 acc[2][2];
};

__device__ __forceinline__ void gemm_tile(
    const float* __restrict__ A, const float* __restrict__ A2,
    const float* __restrict__ W, int K, int N, int mBase, int nBase,
    short (*As)[40], short (*Bs)[40], TileCtx& ctx)
{
    const int t = threadIdx.x;
    const int lane = t & 63;
    const int wave = t >> 6;
    const int wr = wave >> 1, wc = wave & 1;

    const int ar = t >> 2, ac = (t & 3) * 8;   // A staging: row 0..63, kcol {0,8,16,24}
    const int bk = t >> 3, bn0 = (t & 7) * 8;  // B staging: k 0..31, ncol0 {0..56}

    const int lr = lane & 15, lk = (lane >> 4) * 8;

    #pragma unroll
    for (int i = 0; i < 2; ++i)
        #pragma unroll
        for (int j = 0; j < 2; ++j)
            ctx.acc[i][j] = (f32x4){0.f, 0.f, 0.f, 0.f};

    for (int k0 = 0; k0 < K; k0 += 32) {
        // ---- stage A (64 x 32) ----
        {
            const float* ap = A + (long)(mBase + ar) * K + k0 + ac;
            float4 v0 = *(const float4*)ap;
            float4 v1 = *(const float4*)(ap + 4);
            if (A2) {
                const float* ap2 = A2 + (long)(mBase + ar) * K + k0 + ac;
                float4 u0 = *(const float4*)ap2;
                float4 u1 = *(const float4*)(ap2 + 4);
                v0.x += u0.x; v0.y += u0.y; v0.z += u0.z; v0.w += u0.w;
                v1.x += u1.x; v1.y += u1.y; v1.z += u1.z; v1.w += u1.w;
            }
            short tmp[8];
            tmp[0]=f2bf(v0.x); tmp[1]=f2bf(v0.y); tmp[2]=f2bf(v0.z); tmp[3]=f2bf(v0.w);
            tmp[4]=f2bf(v1.x); tmp[5]=f2bf(v1.y); tmp[6]=f2bf(v1.z); tmp[7]=f2bf(v1.w);
            *(bf16x8*)&As[ar][ac] = *(bf16x8*)tmp;
        }
        // ---- stage B transposed: Bs[n][k] = W[k0+k][nBase+n] ----
        {
            const float* wp = W + (long)(k0 + bk) * N + nBase + bn0;
            float4 v0 = *(const float4*)wp;
            float4 v1 = *(const float4*)(wp + 4);
            Bs[bn0 + 0][bk] = f2bf(v0.x);
            Bs[bn0 + 1][bk] = f2bf(v0.y);
            Bs[bn0 + 2][bk] = f2bf(v0.z);
            Bs[bn0 + 3][bk] = f2bf(v0.w);
            Bs[bn0 + 4][bk] = f2bf(v1.x);
            Bs[bn0 + 5][bk] = f2bf(v1.y);
            Bs[bn0 + 6][bk] = f2bf(v1.z);
            Bs[bn0 + 7][bk] = f2bf(v1.w);
        }
        __syncthreads();
        // ---- fragments + MFMA ----
        bf16x8 af[2], bf[2];
        #pragma unroll
        for (int fm = 0; fm < 2; ++fm)
            af[fm] = *(bf16x8*)&As[wr * 32 + fm * 16 + lr][lk];
        #pragma unroll
        for (int fn = 0; fn < 2; ++fn)
            bf[fn] = *(bf16x8*)&Bs[wc * 32 + fn * 16 + lr][lk];
        #pragma unroll
        for (int fm = 0; fm < 2; ++fm)
            #pragma unroll
            for (int fn = 0; fn < 2; ++fn)
                ctx.acc[fm][fn] = __builtin_amdgcn_mfma_f32_16x16x32_bf16(
                    af[fm], bf[fn], ctx.acc[fm][fn], 0, 0, 0);
        __syncthreads();
    }
}

// Generic GEMM: C = (A[+A2]) @ W + bias [+res] [relu]
__global__ __launch_bounds__(256) void gemm_mfma(
    const float* __restrict__ A, const float* __restrict__ A2,
    const float* __restrict__ W, const float* __restrict__ bias,
    const float* __restrict__ res, float* __restrict__ C,
    int K, int N, int relu)
{
    __shared__ short As[64][40];
    __shared__ short Bs[64][40];
    const int mBase = blockIdx.x * 64, nBase = blockIdx.y * 64;
    TileCtx ctx;
    gemm_tile(A, A2, W, K, N, mBase, nBase, As, Bs, ctx);

    const int lane = threadIdx.x & 63;
    const int wave = threadIdx.x >> 6;
    const int wr = wave >> 1, wc = wave & 1;
    #pragma unroll
    for (int fm = 0; fm < 2; ++fm)
        #pragma unroll
        for (int fn = 0; fn < 2; ++fn)
            #pragma unroll
            for (int r = 0; r < 4; ++r) {
                int m = mBase + wr * 32 + fm * 16 + (lane >> 4) * 4 + r;
                int n = nBase + wc * 32 + fn * 16 + (lane & 15);
                float v = ctx.acc[fm][fn][r] + bias[n];
                if (res)  v += res[(long)m * N + n];
                if (relu) v = fmaxf(v, 0.f);
                C[(long)m * N + n] = v;
            }
}

// Fused projections: value = x@Wv+bv ; offraw = (x+pos)@Woff+boff ;
// logits = (x+pos)@Wattn+battn.  grid (85, 10): ny 0-3 value, 4-7 offraw, 8-9 logits.
__global__ __launch_bounds__(256) void proj_mfma(
    const float* __restrict__ x, const float* __restrict__ pos,
    const float* __restrict__ Wv, const float* __restrict__ bv,
    const float* __restrict__ Wof, const float* __restrict__ bof,
    const float* __restrict__ Wat, const float* __restrict__ bat,
    float* __restrict__ value, float* __restrict__ offraw, float* __restrict__ logits)
{
    __shared__ short As[64][40];
    __shared__ short Bs[64][40];
    const int ny = blockIdx.y;
    const float* Wm; const float* bias; float* out;
    const float* A2; int Nout, nb;
    if (ny < 4)      { Wm = Wv;  bias = bv;  out = value;  A2 = nullptr; Nout = 256; nb = ny; }
    else if (ny < 8) { Wm = Wof; bias = bof; out = offraw; A2 = pos;     Nout = 256; nb = ny - 4; }
    else             { Wm = Wat; bias = bat; out = logits; A2 = pos;     Nout = 128; nb = ny - 8; }
    const int mBase = blockIdx.x * 64, nBase = nb * 64;

    TileCtx ctx;
    gemm_tile(x, A2, Wm, 256, Nout, mBase, nBase, As, Bs, ctx);

    const int lane = threadIdx.x & 63;
    const int wave = threadIdx.x >> 6;
    const int wr = wave >> 1, wc = wave & 1;
    #pragma unroll
    for (int fm = 0; fm < 2; ++fm)
        #pragma unroll
        for (int fn = 0; fn < 2; ++fn)
            #pragma unroll
            for (int r = 0; r < 4; ++r) {
                int m = mBase + wr * 32 + fm * 16 + (lane >> 4) * 4 + r;
                int n = nBase + wc * 32 + fn * 16 + (lane & 15);
                out[(long)m * Nout + n] = ctx.acc[fm][fn][r] + bias[n];
            }
}

// ---------------- MSDA sampling (unchanged from round 0) ----------------
__global__ __launch_bounds__(256) void msda_sample(
    const float* __restrict__ value, const float* __restrict__ offraw,
    const float* __restrict__ logits, const float* __restrict__ vr,
    float* __restrict__ out)
{
    const int s = blockIdx.x;
    const int t = threadIdx.x;

    __shared__ float sOff[256];
    __shared__ float sAw[128];

    sOff[t] = offraw[(long)s * 256 + t];
    if (t < 128) sAw[t] = logits[(long)s * 128 + t];
    __syncthreads();

    if (t < 8) {
        float m = -1e30f;
        #pragma unroll
        for (int i = 0; i < 16; ++i) m = fmaxf(m, sAw[t * 16 + i]);
        float sum = 0.f;
        #pragma unroll
        for (int i = 0; i < 16; ++i) { float e = expf(sAw[t * 16 + i] - m); sAw[t * 16 + i] = e; sum += e; }
        float inv = 1.f / sum;
        #pragma unroll
        for (int i = 0; i < 16; ++i) sAw[t * 16 + i] *= inv;
    }
    __syncthreads();

    int ls = (s < 4096) ? 0 : (s < 5120) ? 1 : (s < 5376) ? 2 : 3;
    int Wq = c_HW[ls];
    int rem = s - c_start[ls];
    int qi = rem / Wq, qj = rem % Wq;
    float xh = (qj + 0.5f) / (vr[ls * 2 + 1] * (float)Wq);
    float yh = (qi + 0.5f) / (vr[ls * 2 + 0] * (float)Wq);

    const int h = t >> 5, d = t & 31;
    const float* voff = value + h * 32 + d;
    float acc = 0.f;

    #pragma unroll
    for (int l = 0; l < 4; ++l) {
        const int Wl = c_HW[l];
        const int sl = c_start[l];
        const float fW = (float)Wl;
        const float refx = xh * vr[l * 2 + 1];
        const float refy = yh * vr[l * 2 + 0];
        #pragma unroll
        for (int p = 0; p < 4; ++p) {
            const int oi = ((h * 4 + l) * 4 + p) * 2;
            float lx = refx + sOff[oi]     / fW;
            float ly = refy + sOff[oi + 1] / fW;
            float x = lx * fW - 0.5f;
            float y = ly * fW - 0.5f;
            float x0f = floorf(x), y0f = floorf(y);
            float fx = x - x0f, fy = y - y0f;
            int x0 = (int)x0f, y0 = (int)y0f;
            float aw = sAw[h * 16 + l * 4 + p];

            float v00 = 0.f, v01 = 0.f, v10 = 0.f, v11 = 0.f;
            bool xin0 = (x0 >= 0) & (x0 < Wl);
            bool xin1 = (x0 + 1 >= 0) & (x0 + 1 < Wl);
            bool yin0 = (y0 >= 0) & (y0 < Wl);
            bool yin1 = (y0 + 1 >= 0) & (y0 + 1 < Wl);
            if (xin0 & yin0) v00 = voff[(long)(sl + y0 * Wl + x0) * 256];
            if (xin1 & yin0) v01 = voff[(long)(sl + y0 * Wl + x0 + 1) * 256];
            if (xin0 & yin1) v10 = voff[(long)(sl + (y0 + 1) * Wl + x0) * 256];
            if (xin1 & yin1) v11 = voff[(long)(sl + (y0 + 1) * Wl + x0 + 1) * 256];

            float bi = v00 * (1.f - fx) * (1.f - fy) + v01 * fx * (1.f - fy)
                     + v10 * (1.f - fx) * fy         + v11 * fx * fy;
            acc += aw * bi;
        }
    }
    out[(long)s * 256 + t] = acc;
}

// ---------------- LayerNorm over C=256 ----------------
__global__ __launch_bounds__(256) void ln_k(
    const float* __restrict__ in, const float* __restrict__ g,
    const float* __restrict__ b, float* __restrict__ out)
{
    const int s = blockIdx.x;
    const int t = threadIdx.x;
    float v = in[(long)s * 256 + t];

    __shared__ float red[4];
    __shared__ float red2[4];
    const int wid = t >> 6, lane = t & 63;

    float sum = v;
    #pragma unroll
    for (int o = 32; o > 0; o >>= 1) sum += __shfl_down(sum, o);
    if (lane == 0) red[wid] = sum;
    __syncthreads();
    if (t == 0) red[0] = (red[0] + red[1] + red[2] + red[3]) * (1.f / 256.f);
    __syncthreads();
    const float mean = red[0];

    float dv = v - mean;
    float sq = dv * dv;
    #pragma unroll
    for (int o = 32; o > 0; o >>= 1) sq += __shfl_down(sq, o);
    if (lane == 0) red2[wid] = sq;
    __syncthreads();
    if (t == 0) red2[0] = (red2[0] + red2[1] + red2[2] + red2[3]) * (1.f / 256.f);
    __syncthreads();
    const float var = red2[0];

    out[(long)s * 256 + t] = dv * rsqrtf(var + 1e-5f) * g[t] + b[t];
}

extern "C" void kernel_launch(void* const* d_in, const int* in_sizes, int n_in,
                              void* d_out, int out_size, void* d_ws, size_t ws_size,
                              hipStream_t stream) {
    const float* src   = (const float*)d_in[0];
    const float* pos   = (const float*)d_in[1];
    const float* vr    = (const float*)d_in[2];
    const float* Wv    = (const float*)d_in[5];
    const float* bv    = (const float*)d_in[6];
    const float* Woff  = (const float*)d_in[7];
    const float* boff  = (const float*)d_in[8];
    const float* Wattn = (const float*)d_in[9];
    const float* battn = (const float*)d_in[10];
    const float* Wout  = (const float*)d_in[11];
    const float* bout  = (const float*)d_in[12];
    const float* ln1g  = (const float*)d_in[13];
    const float* ln1b  = (const float*)d_in[14];
    const float* W1    = (const float*)d_in[15];
    const float* b1    = (const float*)d_in[16];
    const float* W2    = (const float*)d_in[17];
    const float* b2    = (const float*)d_in[18];
    const float* ln2g  = (const float*)d_in[19];
    const float* ln2b  = (const float*)d_in[20];

    const int S = S_TOT, C = C_DIM, F = F_DIM;
    const long SC = (long)S * C;

    float* ws     = (float*)d_ws;
    float* xbuf   = ws;                 // S*C
    float* value  = xbuf   + SC;        // S*C
    float* offraw = value  + SC;        // S*C
    float* logits = offraw + SC;        // S*128
    float* msda   = logits + (long)S * 128; // S*C
    float* tmp    = msda   + SC;        // S*C
    float* hbuf   = tmp    + SC;        // S*F

    const float* x = src;
    for (int i = 0; i < N_LAYERS; ++i) {
        const float* Wv_i = Wv + (long)i * C * C;
        const float* Wo_i = Woff + (long)i * C * 256;
        const float* Wa_i = Wattn + (long)i * C * 128;
        const float* Wu_i = Wout + (long)i * C * C;
        const float* W1_i = W1 + (long)i * C * F;
        const float* W2_i = W2 + (long)i * F * C;

        proj_mfma<<<dim3(85, 10), 256, 0, stream>>>(
            x, pos, Wv_i, bv + i * C, Wo_i, boff + i * 256,
            Wa_i, battn + i * 128, value, offraw, logits);

        msda_sample<<<S, 256, 0, stream>>>(value, offraw, logits, vr, msda);

        gemm_mfma<<<dim3(85, 4), 256, 0, stream>>>(
            msda, nullptr, Wu_i, bout + i * C, x, tmp, C, C, 0);

        ln_k<<<S, 256, 0, stream>>>(tmp, ln1g + i * C, ln1b + i * C, xbuf);

        gemm_mfma<<<dim3(85, 16), 256, 0, stream>>>(
            xbuf, nullptr, W1_i, b1 + i * F, nullptr, hbuf, C, F, 1);

        gemm_mfma<<<dim3(85, 4), 256, 0, stream>>>(
            hbuf, nullptr, W2_i, b2 + i * C, xbuf, tmp, F, C, 0);

        float* dst = (i == N_LAYERS - 1) ? (float*)d_out : xbuf;
        ln_k<<<S, 256, 0, stream>>>(tmp, ln2g + i * C, ln2b + i * C, dst);
        x = xbuf;
    }
}

// Round 3
// 666.696 us; speedup vs baseline: 3.0245x; 1.5151x over previous
//
#include <hip/hip_runtime.h>
#include <hip/hip_bf16.h>

#define S_TOT 5440
#define C_DIM 256
#define F_DIM 1024
#define N_LAYERS 6

__device__ __constant__ int c_HW[4]    = {64, 32, 16, 8};
__device__ __constant__ int c_logW[4]  = {6, 5, 4, 3};
__device__ __constant__ int c_start[4] = {0, 4096, 5120, 5376};

typedef __attribute__((ext_vector_type(8))) short bf16x8;
typedef __attribute__((ext_vector_type(4))) float f32x4;

__device__ __forceinline__ short f2bf(float f) {
    __hip_bfloat16 h = __float2bfloat16(f);
    return *reinterpret_cast<short*>(&h);
}

// ============ bf16-MFMA GEMM core (unchanged from round 1) ============
struct TileCtx {
    f32x4 acc[2][2];
};

__device__ __forceinline__ void gemm_tile(
    const float* __restrict__ A, const float* __restrict__ A2,
    const float* __restrict__ W, int K, int N, int mBase, int nBase,
    short (*As)[40], short (*Bs)[40], TileCtx& ctx)
{
    const int t = threadIdx.x;
    const int lane = t & 63;
    const int wave = t >> 6;
    const int wr = wave >> 1, wc = wave & 1;

    const int ar = t >> 2, ac = (t & 3) * 8;
    const int bk = t >> 3, bn0 = (t & 7) * 8;

    const int lr = lane & 15, lk = (lane >> 4) * 8;

    #pragma unroll
    for (int i = 0; i < 2; ++i)
        #pragma unroll
        for (int j = 0; j < 2; ++j)
            ctx.acc[i][j] = (f32x4){0.f, 0.f, 0.f, 0.f};

    for (int k0 = 0; k0 < K; k0 += 32) {
        {
            const float* ap = A + (long)(mBase + ar) * K + k0 + ac;
            float4 v0 = *(const float4*)ap;
            float4 v1 = *(const float4*)(ap + 4);
            if (A2) {
                const float* ap2 = A2 + (long)(mBase + ar) * K + k0 + ac;
                float4 u0 = *(const float4*)ap2;
                float4 u1 = *(const float4*)(ap2 + 4);
                v0.x += u0.x; v0.y += u0.y; v0.z += u0.z; v0.w += u0.w;
                v1.x += u1.x; v1.y += u1.y; v1.z += u1.z; v1.w += u1.w;
            }
            short tmp[8];
            tmp[0]=f2bf(v0.x); tmp[1]=f2bf(v0.y); tmp[2]=f2bf(v0.z); tmp[3]=f2bf(v0.w);
            tmp[4]=f2bf(v1.x); tmp[5]=f2bf(v1.y); tmp[6]=f2bf(v1.z); tmp[7]=f2bf(v1.w);
            *(bf16x8*)&As[ar][ac] = *(bf16x8*)tmp;
        }
        {
            const float* wp = W + (long)(k0 + bk) * N + nBase + bn0;
            float4 v0 = *(const float4*)wp;
            float4 v1 = *(const float4*)(wp + 4);
            Bs[bn0 + 0][bk] = f2bf(v0.x);
            Bs[bn0 + 1][bk] = f2bf(v0.y);
            Bs[bn0 + 2][bk] = f2bf(v0.z);
            Bs[bn0 + 3][bk] = f2bf(v0.w);
            Bs[bn0 + 4][bk] = f2bf(v1.x);
            Bs[bn0 + 5][bk] = f2bf(v1.y);
            Bs[bn0 + 6][bk] = f2bf(v1.z);
            Bs[bn0 + 7][bk] = f2bf(v1.w);
        }
        __syncthreads();
        bf16x8 af[2], bf[2];
        #pragma unroll
        for (int fm = 0; fm < 2; ++fm)
            af[fm] = *(bf16x8*)&As[wr * 32 + fm * 16 + lr][lk];
        #pragma unroll
        for (int fn = 0; fn < 2; ++fn)
            bf[fn] = *(bf16x8*)&Bs[wc * 32 + fn * 16 + lr][lk];
        #pragma unroll
        for (int fm = 0; fm < 2; ++fm)
            #pragma unroll
            for (int fn = 0; fn < 2; ++fn)
                ctx.acc[fm][fn] = __builtin_amdgcn_mfma_f32_16x16x32_bf16(
                    af[fm], bf[fn], ctx.acc[fm][fn], 0, 0, 0);
        __syncthreads();
    }
}

__global__ __launch_bounds__(256) void gemm_mfma(
    const float* __restrict__ A, const float* __restrict__ A2,
    const float* __restrict__ W, const float* __restrict__ bias,
    const float* __restrict__ res, float* __restrict__ C,
    int K, int N, int relu)
{
    __shared__ short As[64][40];
    __shared__ short Bs[64][40];
    const int mBase = blockIdx.x * 64, nBase = blockIdx.y * 64;
    TileCtx ctx;
    gemm_tile(A, A2, W, K, N, mBase, nBase, As, Bs, ctx);

    const int lane = threadIdx.x & 63;
    const int wave = threadIdx.x >> 6;
    const int wr = wave >> 1, wc = wave & 1;
    #pragma unroll
    for (int fm = 0; fm < 2; ++fm)
        #pragma unroll
        for (int fn = 0; fn < 2; ++fn)
            #pragma unroll
            for (int r = 0; r < 4; ++r) {
                int m = mBase + wr * 32 + fm * 16 + (lane >> 4) * 4 + r;
                int n = nBase + wc * 32 + fn * 16 + (lane & 15);
                float v = ctx.acc[fm][fn][r] + bias[n];
                if (res)  v += res[(long)m * N + n];
                if (relu) v = fmaxf(v, 0.f);
                C[(long)m * N + n] = v;
            }
}

__global__ __launch_bounds__(256) void proj_mfma(
    const float* __restrict__ x, const float* __restrict__ pos,
    const float* __restrict__ Wv, const float* __restrict__ bv,
    const float* __restrict__ Wof, const float* __restrict__ bof,
    const float* __restrict__ Wat, const float* __restrict__ bat,
    float* __restrict__ value, float* __restrict__ offraw, float* __restrict__ logits)
{
    __shared__ short As[64][40];
    __shared__ short Bs[64][40];
    const int ny = blockIdx.y;
    const float* Wm; const float* bias; float* out;
    const float* A2; int Nout, nb;
    if (ny < 4)      { Wm = Wv;  bias = bv;  out = value;  A2 = nullptr; Nout = 256; nb = ny; }
    else if (ny < 8) { Wm = Wof; bias = bof; out = offraw; A2 = pos;     Nout = 256; nb = ny - 4; }
    else             { Wm = Wat; bias = bat; out = logits; A2 = pos;     Nout = 128; nb = ny - 8; }
    const int mBase = blockIdx.x * 64, nBase = nb * 64;

    TileCtx ctx;
    gemm_tile(x, A2, Wm, 256, Nout, mBase, nBase, As, Bs, ctx);

    const int lane = threadIdx.x & 63;
    const int wave = threadIdx.x >> 6;
    const int wr = wave >> 1, wc = wave & 1;
    #pragma unroll
    for (int fm = 0; fm < 2; ++fm)
        #pragma unroll
        for (int fn = 0; fn < 2; ++fn)
            #pragma unroll
            for (int r = 0; r < 4; ++r) {
                int m = mBase + wr * 32 + fm * 16 + (lane >> 4) * 4 + r;
                int n = nBase + wc * 32 + fn * 16 + (lane & 15);
                out[(long)m * Nout + n] = ctx.acc[fm][fn][r] + bias[n];
            }
}

// ---------------- MSDA sampling v2 ----------------
// Phase 1 (t<128): softmax + coordinate math for (h,pt); store 4 clamped
// indices + 4 aw-premultiplied weights in LDS.
// Phase 2 (all 256): t = pg*64 + h*8 + dq; gather float4s, partial-reduce.
__global__ __launch_bounds__(256) void msda_sample(
    const float* __restrict__ value, const float* __restrict__ offraw,
    const float* __restrict__ logits, const float* __restrict__ vr,
    float* __restrict__ out)
{
    const int s = blockIdx.x;
    const int t = threadIdx.x;

    __shared__ int4   sIdx[128];
    __shared__ float4 sW[128];
    __shared__ float4 sPart[192];

    if (t < 128) {
        const int pt = t & 15;
        const int l = pt >> 2;

        // softmax over the 16-lane group (one head)
        float lg = logits[s * 128 + t];
        float m = lg;
        #pragma unroll
        for (int o = 1; o < 16; o <<= 1) m = fmaxf(m, __shfl_xor(m, o));
        float e = expf(lg - m);
        float sum = e;
        #pragma unroll
        for (int o = 1; o < 16; o <<= 1) sum += __shfl_xor(sum, o);
        float aw = e / sum;

        // reference point for query s
        int ls = (s < 4096) ? 0 : (s < 5120) ? 1 : (s < 5376) ? 2 : 3;
        int lw = c_logW[ls];
        int Wq = c_HW[ls];
        int rem = s - c_start[ls];
        int qi = rem >> lw, qj = rem & (Wq - 1);
        float xh = (qj + 0.5f) / (vr[ls * 2 + 1] * (float)Wq);
        float yh = (qi + 0.5f) / (vr[ls * 2 + 0] * (float)Wq);

        const int Wl = c_HW[l], sl = c_start[l];
        const float fW = (float)Wl;
        float refx = xh * vr[l * 2 + 1];
        float refy = yh * vr[l * 2 + 0];
        float ox = offraw[s * 256 + t * 2];
        float oy = offraw[s * 256 + t * 2 + 1];
        float x = refx * fW + ox - 0.5f;
        float y = refy * fW + oy - 0.5f;
        float x0f = floorf(x), y0f = floorf(y);
        float fx = x - x0f, fy = y - y0f;
        int x0 = (int)x0f, y0 = (int)y0f;
        int x1 = x0 + 1, y1 = y0 + 1;
        float vx0 = (x0 >= 0 && x0 < Wl) ? 1.f : 0.f;
        float vx1 = (x1 >= 0 && x1 < Wl) ? 1.f : 0.f;
        float vy0 = (y0 >= 0 && y0 < Wl) ? 1.f : 0.f;
        float vy1 = (y1 >= 0 && y1 < Wl) ? 1.f : 0.f;
        int cx0 = min(max(x0, 0), Wl - 1), cx1 = min(max(x1, 0), Wl - 1);
        int cy0 = min(max(y0, 0), Wl - 1), cy1 = min(max(y1, 0), Wl - 1);

        int4 id;
        id.x = sl + cy0 * Wl + cx0;
        id.y = sl + cy0 * Wl + cx1;
        id.z = sl + cy1 * Wl + cx0;
        id.w = sl + cy1 * Wl + cx1;
        sIdx[t] = id;
        float4 w4;
        w4.x = aw * (1.f - fx) * (1.f - fy) * vx0 * vy0;
        w4.y = aw * fx * (1.f - fy) * vx1 * vy0;
        w4.z = aw * (1.f - fx) * fy * vx0 * vy1;
        w4.w = aw * fx * fy * vx1 * vy1;
        sW[t] = w4;
    }
    __syncthreads();

    // Phase 2: gather
    const int pg = t >> 6;          // level group (wave)
    const int h  = (t >> 3) & 7;
    const int dq = t & 7;
    const int cb = h * 32 + dq * 4; // channel base

    f32x4 acc = (f32x4){0.f, 0.f, 0.f, 0.f};
    #pragma unroll
    for (int p = 0; p < 4; ++p) {
        const int e = h * 16 + pg * 4 + p;
        int4 id = sIdx[e];
        float4 w = sW[e];
        f32x4 v0 = *(const f32x4*)(value + id.x * 256 + cb);
        f32x4 v1 = *(const f32x4*)(value + id.y * 256 + cb);
        f32x4 v2 = *(const f32x4*)(value + id.z * 256 + cb);
        f32x4 v3 = *(const f32x4*)(value + id.w * 256 + cb);
        acc += w.x * v0 + w.y * v1 + w.z * v2 + w.w * v3;
    }

    if (pg > 0) {
        float4 st; st.x = acc[0]; st.y = acc[1]; st.z = acc[2]; st.w = acc[3];
        sPart[(pg - 1) * 64 + (t & 63)] = st;
    }
    __syncthreads();
    if (pg == 0) {
        float4 p0 = sPart[t], p1 = sPart[64 + t], p2 = sPart[128 + t];
        acc[0] += p0.x + p1.x + p2.x;
        acc[1] += p0.y + p1.y + p2.y;
        acc[2] += p0.z + p1.z + p2.z;
        acc[3] += p0.w + p1.w + p2.w;
        *(f32x4*)(out + (long)s * 256 + cb) = acc;
    }
}

// ---------------- LayerNorm: one wave per row, float4 per lane ----------------
__global__ __launch_bounds__(256) void ln4(
    const float* __restrict__ in, const float* __restrict__ g,
    const float* __restrict__ b, float* __restrict__ out)
{
    const int wave = threadIdx.x >> 6, lane = threadIdx.x & 63;
    const int s = blockIdx.x * 4 + wave;
    f32x4 v = *(const f32x4*)(in + (long)s * 256 + lane * 4);

    float sum = v[0] + v[1] + v[2] + v[3];
    #pragma unroll
    for (int o = 1; o < 64; o <<= 1) sum += __shfl_xor(sum, o);
    const float mean = sum * (1.f / 256.f);

    f32x4 d = v - mean;
    float sq = d[0]*d[0] + d[1]*d[1] + d[2]*d[2] + d[3]*d[3];
    #pragma unroll
    for (int o = 1; o < 64; o <<= 1) sq += __shfl_xor(sq, o);
    const float rstd = rsqrtf(sq * (1.f / 256.f) + 1e-5f);

    f32x4 gg = *(const f32x4*)(g + lane * 4);
    f32x4 bb = *(const f32x4*)(b + lane * 4);
    f32x4 o4 = d * rstd * gg + bb;
    *(f32x4*)(out + (long)s * 256 + lane * 4) = o4;
}

extern "C" void kernel_launch(void* const* d_in, const int* in_sizes, int n_in,
                              void* d_out, int out_size, void* d_ws, size_t ws_size,
                              hipStream_t stream) {
    const float* src   = (const float*)d_in[0];
    const float* pos   = (const float*)d_in[1];
    const float* vr    = (const float*)d_in[2];
    const float* Wv    = (const float*)d_in[5];
    const float* bv    = (const float*)d_in[6];
    const float* Woff  = (const float*)d_in[7];
    const float* boff  = (const float*)d_in[8];
    const float* Wattn = (const float*)d_in[9];
    const float* battn = (const float*)d_in[10];
    const float* Wout  = (const float*)d_in[11];
    const float* bout  = (const float*)d_in[12];
    const float* ln1g  = (const float*)d_in[13];
    const float* ln1b  = (const float*)d_in[14];
    const float* W1    = (const float*)d_in[15];
    const float* b1    = (const float*)d_in[16];
    const float* W2    = (const float*)d_in[17];
    const float* b2    = (const float*)d_in[18];
    const float* ln2g  = (const float*)d_in[19];
    const float* ln2b  = (const float*)d_in[20];

    const int S = S_TOT, C = C_DIM, F = F_DIM;
    const long SC = (long)S * C;

    float* ws     = (float*)d_ws;
    float* xbuf   = ws;
    float* value  = xbuf   + SC;
    float* offraw = value  + SC;
    float* logits = offraw + SC;
    float* msda   = logits + (long)S * 128;
    float* tmp    = msda   + SC;
    float* hbuf   = tmp    + SC;

    const float* x = src;
    for (int i = 0; i < N_LAYERS; ++i) {
        const float* Wv_i = Wv + (long)i * C * C;
        const float* Wo_i = Woff + (long)i * C * 256;
        const float* Wa_i = Wattn + (long)i * C * 128;
        const float* Wu_i = Wout + (long)i * C * C;
        const float* W1_i = W1 + (long)i * C * F;
        const float* W2_i = W2 + (long)i * F * C;

        proj_mfma<<<dim3(85, 10), 256, 0, stream>>>(
            x, pos, Wv_i, bv + i * C, Wo_i, boff + i * 256,
            Wa_i, battn + i * 128, value, offraw, logits);

        msda_sample<<<S, 256, 0, stream>>>(value, offraw, logits, vr, msda);

        gemm_mfma<<<dim3(85, 4), 256, 0, stream>>>(
            msda, nullptr, Wu_i, bout + i * C, x, tmp, C, C, 0);

        ln4<<<S / 4, 256, 0, stream>>>(tmp, ln1g + i * C, ln1b + i * C, xbuf);

        gemm_mfma<<<dim3(85, 16), 256, 0, stream>>>(
            xbuf, nullptr, W1_i, b1 + i * F, nullptr, hbuf, C, F, 1);

        gemm_mfma<<<dim3(85, 4), 256, 0, stream>>>(
            hbuf, nullptr, W2_i, b2 + i * C, xbuf, tmp, F, C, 0);

        float* dst = (i == N_LAYERS - 1) ? (float*)d_out : xbuf;
        ln4<<<S / 4, 256, 0, stream>>>(tmp, ln2g + i * C, ln2b + i * C, dst);
        x = xbuf;
    }
}

// Round 4
// 508.107 us; speedup vs baseline: 3.9685x; 1.3121x over previous
//
#include <hip/hip_runtime.h>
#include <hip/hip_bf16.h>

#define S_TOT 5440
#define C_DIM 256
#define F_DIM 1024
#define N_LAYERS 6

__device__ __constant__ int c_HW[4]    = {64, 32, 16, 8};
__device__ __constant__ int c_logW[4]  = {6, 5, 4, 3};
__device__ __constant__ int c_start[4] = {0, 4096, 5120, 5376};

typedef __attribute__((ext_vector_type(8))) short bf16x8;
typedef __attribute__((ext_vector_type(4))) float f32x4;

__device__ __forceinline__ short f2bf(float f) {
    __hip_bfloat16 h = __float2bfloat16(f);
    return *reinterpret_cast<short*>(&h);
}

// ---------------- weight prep: fp32 [K][N] -> bf16 [N][K], all 36 matrices ----------------
__global__ __launch_bounds__(256) void prep_weights(
    const float* __restrict__ Wv, const float* __restrict__ Woff,
    const float* __restrict__ Wattn, const float* __restrict__ Wout,
    const float* __restrict__ W1, const float* __restrict__ W2,
    unsigned short* __restrict__ WT)
{
    __shared__ short T[64][72];
    const int bid = blockIdx.x;
    const int layer = bid / 184;
    const int r = bid % 184;
    const float* src; unsigned short* dst; int K, N, kb, nb;
    if (r < 16)       { src = Wv    + (long)layer*65536;  dst = WT + 0       + (long)layer*65536;  K=256;  N=256;  kb=r&3;        nb=r>>2; }
    else if (r < 32)  { src = Woff  + (long)layer*65536;  dst = WT + 393216  + (long)layer*65536;  K=256;  N=256;  kb=(r-16)&3;   nb=(r-16)>>2; }
    else if (r < 40)  { src = Wattn + (long)layer*32768;  dst = WT + 786432  + (long)layer*32768;  K=256;  N=128;  kb=(r-32)&3;   nb=(r-32)>>2; }
    else if (r < 56)  { src = Wout  + (long)layer*65536;  dst = WT + 983040  + (long)layer*65536;  K=256;  N=256;  kb=(r-40)&3;   nb=(r-40)>>2; }
    else if (r < 120) { src = W1    + (long)layer*262144; dst = WT + 1376256 + (long)layer*262144; K=256;  N=1024; kb=(r-56)&3;   nb=(r-56)>>2; }
    else              { src = W2    + (long)layer*262144; dst = WT + 2949120 + (long)layer*262144; K=1024; N=256;  kb=(r-120)&15; nb=(r-120)>>4; }
    const int k0 = kb * 64, n0 = nb * 64;
    const int t = threadIdx.x;
    {
        const int row = t >> 2, cg = (t & 3) * 16;
        const float* sp = src + (long)(k0 + row) * N + n0 + cg;
        float4 v0 = *(const float4*)sp;
        float4 v1 = *(const float4*)(sp + 4);
        float4 v2 = *(const float4*)(sp + 8);
        float4 v3 = *(const float4*)(sp + 12);
        short tmp[16];
        tmp[0]=f2bf(v0.x); tmp[1]=f2bf(v0.y); tmp[2]=f2bf(v0.z); tmp[3]=f2bf(v0.w);
        tmp[4]=f2bf(v1.x); tmp[5]=f2bf(v1.y); tmp[6]=f2bf(v1.z); tmp[7]=f2bf(v1.w);
        tmp[8]=f2bf(v2.x); tmp[9]=f2bf(v2.y); tmp[10]=f2bf(v2.z); tmp[11]=f2bf(v2.w);
        tmp[12]=f2bf(v3.x); tmp[13]=f2bf(v3.y); tmp[14]=f2bf(v3.z); tmp[15]=f2bf(v3.w);
        *(bf16x8*)&T[row][cg]     = *(bf16x8*)&tmp[0];
        *(bf16x8*)&T[row][cg + 8] = *(bf16x8*)&tmp[8];
    }
    __syncthreads();
    {
        const int n = t >> 2, kg = (t & 3) * 16;
        short o[16];
        #pragma unroll
        for (int j = 0; j < 16; ++j) o[j] = T[kg + j][n];
        unsigned short* dp = dst + (long)(n0 + n) * K + k0 + kg;
        *(bf16x8*)dp       = *(bf16x8*)&o[0];
        *(bf16x8*)(dp + 8) = *(bf16x8*)&o[8];
    }
}

// ---------------- layer-0 activation prep ----------------
__global__ __launch_bounds__(256) void prep_x0(
    const float* __restrict__ src, const float* __restrict__ pos,
    unsigned short* __restrict__ x_bf, unsigned short* __restrict__ xp_bf)
{
    const long i = ((long)blockIdx.x * 256 + threadIdx.x) * 4;
    float4 s = *(const float4*)(src + i);
    float4 p = *(const float4*)(pos + i);
    ushort4 a, b;
    a.x = f2bf(s.x); a.y = f2bf(s.y); a.z = f2bf(s.z); a.w = f2bf(s.w);
    b.x = f2bf(s.x + p.x); b.y = f2bf(s.y + p.y); b.z = f2bf(s.z + p.z); b.w = f2bf(s.w + p.w);
    *(ushort4*)(x_bf + i) = a;
    *(ushort4*)(xp_bf + i) = b;
}

// ============ bf16 GEMM core: 64x128 tile, BK=64, 4 waves (2x2), wave=32x64 ============
struct Acc { f32x4 a[2][4]; };

__device__ __forceinline__ void gemm_core_bf(
    const unsigned short* __restrict__ A, const unsigned short* __restrict__ Bt,
    int K, int mBase, int nBase, short (*As)[72], short (*Bs)[72], Acc& acc)
{
    const int t = threadIdx.x;
    const int lane = t & 63;
    const int wave = t >> 6;
    const int wr = wave >> 1, wc = wave & 1;
    const int lr = lane & 15;

    #pragma unroll
    for (int i = 0; i < 2; ++i)
        #pragma unroll
        for (int j = 0; j < 4; ++j)
            acc.a[i][j] = (f32x4){0.f, 0.f, 0.f, 0.f};

    for (int k0 = 0; k0 < K; k0 += 64) {
        bf16x8 ra[2], rb[4];
        #pragma unroll
        for (int q = 0; q < 2; ++q) {
            int flat = q * 256 + t, row = flat >> 3, cg = (flat & 7) * 8;
            ra[q] = *(const bf16x8*)(A + (long)(mBase + row) * K + k0 + cg);
        }
        #pragma unroll
        for (int q = 0; q < 4; ++q) {
            int flat = q * 256 + t, row = flat >> 3, cg = (flat & 7) * 8;
            rb[q] = *(const bf16x8*)(Bt + (long)(nBase + row) * K + k0 + cg);
        }
        __syncthreads();   // prev iter's frag reads done
        #pragma unroll
        for (int q = 0; q < 2; ++q) {
            int flat = q * 256 + t, row = flat >> 3, cg = (flat & 7) * 8;
            *(bf16x8*)&As[row][cg] = ra[q];
        }
        #pragma unroll
        for (int q = 0; q < 4; ++q) {
            int flat = q * 256 + t, row = flat >> 3, cg = (flat & 7) * 8;
            *(bf16x8*)&Bs[row][cg] = rb[q];
        }
        __syncthreads();
        #pragma unroll
        for (int kk = 0; kk < 2; ++kk) {
            const int lk = kk * 32 + (lane >> 4) * 8;
            bf16x8 af[2], bfr[4];
            #pragma unroll
            for (int fm = 0; fm < 2; ++fm)
                af[fm] = *(bf16x8*)&As[wr * 32 + fm * 16 + lr][lk];
            #pragma unroll
            for (int fn = 0; fn < 4; ++fn)
                bfr[fn] = *(bf16x8*)&Bs[wc * 64 + fn * 16 + lr][lk];
            #pragma unroll
            for (int fm = 0; fm < 2; ++fm)
                #pragma unroll
                for (int fn = 0; fn < 4; ++fn)
                    acc.a[fm][fn] = __builtin_amdgcn_mfma_f32_16x16x32_bf16(
                        af[fm], bfr[fn], acc.a[fm][fn], 0, 0, 0);
        }
    }
}

// Generic: out = A @ BtT + bias [+res] [relu]; outF fp32 and/or outB bf16
__global__ __launch_bounds__(256) void gemm_bf(
    const unsigned short* __restrict__ A, const unsigned short* __restrict__ Bt,
    const float* __restrict__ bias, const float* __restrict__ res,
    float* __restrict__ outF, unsigned short* __restrict__ outB,
    int K, int N, int relu)
{
    __shared__ short As[64][72];
    __shared__ short Bs[128][72];
    const int mBase = blockIdx.x * 64, nBase = blockIdx.y * 128;
    Acc acc;
    gemm_core_bf(A, Bt, K, mBase, nBase, As, Bs, acc);

    const int lane = threadIdx.x & 63;
    const int wave = threadIdx.x >> 6;
    const int wr = wave >> 1, wc = wave & 1;
    #pragma unroll
    for (int fm = 0; fm < 2; ++fm)
        #pragma unroll
        for (int fn = 0; fn < 4; ++fn)
            #pragma unroll
            for (int r = 0; r < 4; ++r) {
                int m = mBase + wr * 32 + fm * 16 + (lane >> 4) * 4 + r;
                int n = nBase + wc * 64 + fn * 16 + (lane & 15);
                float v = acc.a[fm][fn][r] + bias[n];
                if (res)  v += res[(long)m * N + n];
                if (relu) v = fmaxf(v, 0.f);
                if (outF) outF[(long)m * N + n] = v;
                if (outB) outB[(long)m * N + n] = (unsigned short)f2bf(v);
            }
}

// Fused projections: ny 0-1 value(x_bf), 2-3 offraw(xp_bf), 4 logits(xp_bf)
__global__ __launch_bounds__(256) void proj_bf(
    const unsigned short* __restrict__ x_bf, const unsigned short* __restrict__ xp_bf,
    const unsigned short* __restrict__ WvT, const float* __restrict__ bv,
    const unsigned short* __restrict__ WofT, const float* __restrict__ bof,
    const unsigned short* __restrict__ WatT, const float* __restrict__ bat,
    float* __restrict__ value, float* __restrict__ offraw, float* __restrict__ logits)
{
    __shared__ short As[64][72];
    __shared__ short Bs[128][72];
    const int ny = blockIdx.y;
    const unsigned short* Ap; const unsigned short* Bp;
    const float* bias; float* out; int Nout, nb;
    if (ny < 2)      { Ap = x_bf;  Bp = WvT;  bias = bv;  out = value;  Nout = 256; nb = ny; }
    else if (ny < 4) { Ap = xp_bf; Bp = WofT; bias = bof; out = offraw; Nout = 256; nb = ny - 2; }
    else             { Ap = xp_bf; Bp = WatT; bias = bat; out = logits; Nout = 128; nb = 0; }
    const int mBase = blockIdx.x * 64, nBase = nb * 128;

    Acc acc;
    gemm_core_bf(Ap, Bp, 256, mBase, nBase, As, Bs, acc);

    const int lane = threadIdx.x & 63;
    const int wave = threadIdx.x >> 6;
    const int wr = wave >> 1, wc = wave & 1;
    #pragma unroll
    for (int fm = 0; fm < 2; ++fm)
        #pragma unroll
        for (int fn = 0; fn < 4; ++fn)
            #pragma unroll
            for (int r = 0; r < 4; ++r) {
                int m = mBase + wr * 32 + fm * 16 + (lane >> 4) * 4 + r;
                int n = nBase + wc * 64 + fn * 16 + (lane & 15);
                out[(long)m * Nout + n] = acc.a[fm][fn][r] + bias[n];
            }
}

// ---------------- MSDA sampling (phase-split; bf16 output) ----------------
__global__ __launch_bounds__(256) void msda_sample(
    const float* __restrict__ value, const float* __restrict__ offraw,
    const float* __restrict__ logits, const float* __restrict__ vr,
    unsigned short* __restrict__ outB)
{
    const int s = blockIdx.x;
    const int t = threadIdx.x;

    __shared__ int4   sIdx[128];
    __shared__ float4 sW[128];
    __shared__ float4 sPart[192];

    if (t < 128) {
        const int pt = t & 15;
        const int l = pt >> 2;

        float lg = logits[s * 128 + t];
        float m = lg;
        #pragma unroll
        for (int o = 1; o < 16; o <<= 1) m = fmaxf(m, __shfl_xor(m, o));
        float e = expf(lg - m);
        float sum = e;
        #pragma unroll
        for (int o = 1; o < 16; o <<= 1) sum += __shfl_xor(sum, o);
        float aw = e / sum;

        int ls = (s < 4096) ? 0 : (s < 5120) ? 1 : (s < 5376) ? 2 : 3;
        int lw = c_logW[ls];
        int Wq = c_HW[ls];
        int rem = s - c_start[ls];
        int qi = rem >> lw, qj = rem & (Wq - 1);
        float xh = (qj + 0.5f) / (vr[ls * 2 + 1] * (float)Wq);
        float yh = (qi + 0.5f) / (vr[ls * 2 + 0] * (float)Wq);

        const int Wl = c_HW[l], sl = c_start[l];
        const float fW = (float)Wl;
        float refx = xh * vr[l * 2 + 1];
        float refy = yh * vr[l * 2 + 0];
        float ox = offraw[s * 256 + t * 2];
        float oy = offraw[s * 256 + t * 2 + 1];
        float x = refx * fW + ox - 0.5f;
        float y = refy * fW + oy - 0.5f;
        float x0f = floorf(x), y0f = floorf(y);
        float fx = x - x0f, fy = y - y0f;
        int x0 = (int)x0f, y0 = (int)y0f;
        int x1 = x0 + 1, y1 = y0 + 1;
        float vx0 = (x0 >= 0 && x0 < Wl) ? 1.f : 0.f;
        float vx1 = (x1 >= 0 && x1 < Wl) ? 1.f : 0.f;
        float vy0 = (y0 >= 0 && y0 < Wl) ? 1.f : 0.f;
        float vy1 = (y1 >= 0 && y1 < Wl) ? 1.f : 0.f;
        int cx0 = min(max(x0, 0), Wl - 1), cx1 = min(max(x1, 0), Wl - 1);
        int cy0 = min(max(y0, 0), Wl - 1), cy1 = min(max(y1, 0), Wl - 1);

        int4 id;
        id.x = sl + cy0 * Wl + cx0;
        id.y = sl + cy0 * Wl + cx1;
        id.z = sl + cy1 * Wl + cx0;
        id.w = sl + cy1 * Wl + cx1;
        sIdx[t] = id;
        float4 w4;
        w4.x = aw * (1.f - fx) * (1.f - fy) * vx0 * vy0;
        w4.y = aw * fx * (1.f - fy) * vx1 * vy0;
        w4.z = aw * (1.f - fx) * fy * vx0 * vy1;
        w4.w = aw * fx * fy * vx1 * vy1;
        sW[t] = w4;
    }
    __syncthreads();

    const int pg = t >> 6;
    const int h  = (t >> 3) & 7;
    const int dq = t & 7;
    const int cb = h * 32 + dq * 4;

    f32x4 acc = (f32x4){0.f, 0.f, 0.f, 0.f};
    #pragma unroll
    for (int p = 0; p < 4; ++p) {
        const int e = h * 16 + pg * 4 + p;
        int4 id = sIdx[e];
        float4 w = sW[e];
        f32x4 v0 = *(const f32x4*)(value + id.x * 256 + cb);
        f32x4 v1 = *(const f32x4*)(value + id.y * 256 + cb);
        f32x4 v2 = *(const f32x4*)(value + id.z * 256 + cb);
        f32x4 v3 = *(const f32x4*)(value + id.w * 256 + cb);
        acc += w.x * v0 + w.y * v1 + w.z * v2 + w.w * v3;
    }

    if (pg > 0) {
        float4 st; st.x = acc[0]; st.y = acc[1]; st.z = acc[2]; st.w = acc[3];
        sPart[(pg - 1) * 64 + (t & 63)] = st;
    }
    __syncthreads();
    if (pg == 0) {
        float4 p0 = sPart[t], p1 = sPart[64 + t], p2 = sPart[128 + t];
        acc[0] += p0.x + p1.x + p2.x;
        acc[1] += p0.y + p1.y + p2.y;
        acc[2] += p0.z + p1.z + p2.z;
        acc[3] += p0.w + p1.w + p2.w;
        ushort4 o;
        o.x = (unsigned short)f2bf(acc[0]);
        o.y = (unsigned short)f2bf(acc[1]);
        o.z = (unsigned short)f2bf(acc[2]);
        o.w = (unsigned short)f2bf(acc[3]);
        *(ushort4*)(outB + (long)s * 256 + cb) = o;
    }
}

// ---------------- LayerNorm: wave/row; fp32 out + bf16 out + optional bf16(x+pos) ----------------
__global__ __launch_bounds__(256) void ln4(
    const float* __restrict__ in, const float* __restrict__ g,
    const float* __restrict__ b, float* __restrict__ outF,
    unsigned short* __restrict__ outB, const float* __restrict__ pos,
    unsigned short* __restrict__ outXp)
{
    const int wave = threadIdx.x >> 6, lane = threadIdx.x & 63;
    const int s = blockIdx.x * 4 + wave;
    f32x4 v = *(const f32x4*)(in + (long)s * 256 + lane * 4);

    float sum = v[0] + v[1] + v[2] + v[3];
    #pragma unroll
    for (int o = 1; o < 64; o <<= 1) sum += __shfl_xor(sum, o);
    const float mean = sum * (1.f / 256.f);

    f32x4 d = v - mean;
    float sq = d[0]*d[0] + d[1]*d[1] + d[2]*d[2] + d[3]*d[3];
    #pragma unroll
    for (int o = 1; o < 64; o <<= 1) sq += __shfl_xor(sq, o);
    const float rstd = rsqrtf(sq * (1.f / 256.f) + 1e-5f);

    f32x4 gg = *(const f32x4*)(g + lane * 4);
    f32x4 bb = *(const f32x4*)(b + lane * 4);
    f32x4 o4 = d * rstd * gg + bb;
    outF[(long)s * 256 + lane * 4 + 0] = o4[0];
    outF[(long)s * 256 + lane * 4 + 1] = o4[1];
    outF[(long)s * 256 + lane * 4 + 2] = o4[2];
    outF[(long)s * 256 + lane * 4 + 3] = o4[3];
    if (outB) {
        ushort4 ob;
        ob.x = (unsigned short)f2bf(o4[0]); ob.y = (unsigned short)f2bf(o4[1]);
        ob.z = (unsigned short)f2bf(o4[2]); ob.w = (unsigned short)f2bf(o4[3]);
        *(ushort4*)(outB + (long)s * 256 + lane * 4) = ob;
    }
    if (outXp) {
        f32x4 p = *(const f32x4*)(pos + (long)s * 256 + lane * 4);
        f32x4 xp = o4 + p;
        ushort4 op;
        op.x = (unsigned short)f2bf(xp[0]); op.y = (unsigned short)f2bf(xp[1]);
        op.z = (unsigned short)f2bf(xp[2]); op.w = (unsigned short)f2bf(xp[3]);
        *(ushort4*)(outXp + (long)s * 256 + lane * 4) = op;
    }
}

extern "C" void kernel_launch(void* const* d_in, const int* in_sizes, int n_in,
                              void* d_out, int out_size, void* d_ws, size_t ws_size,
                              hipStream_t stream) {
    const float* src   = (const float*)d_in[0];
    const float* pos   = (const float*)d_in[1];
    const float* vr    = (const float*)d_in[2];
    const float* Wv    = (const float*)d_in[5];
    const float* bv    = (const float*)d_in[6];
    const float* Woff  = (const float*)d_in[7];
    const float* boff  = (const float*)d_in[8];
    const float* Wattn = (const float*)d_in[9];
    const float* battn = (const float*)d_in[10];
    const float* Wout  = (const float*)d_in[11];
    const float* bout  = (const float*)d_in[12];
    const float* ln1g  = (const float*)d_in[13];
    const float* ln1b  = (const float*)d_in[14];
    const float* W1    = (const float*)d_in[15];
    const float* b1    = (const float*)d_in[16];
    const float* W2    = (const float*)d_in[17];
    const float* b2    = (const float*)d_in[18];
    const float* ln2g  = (const float*)d_in[19];
    const float* ln2b  = (const float*)d_in[20];

    const int S = S_TOT, C = C_DIM;
    const long SC = (long)S * C;

    // fp32 region
    float* ws     = (float*)d_ws;
    float* xbuf   = ws;                       // SC
    float* tmp    = xbuf + SC;                // SC
    float* value  = tmp + SC;                 // SC
    float* offraw = value + SC;               // SC
    float* logits = offraw + SC;              // S*128
    float* fend   = logits + (long)S * 128;
    // bf16 region
    unsigned short* x_bf  = (unsigned short*)fend;           // SC
    unsigned short* xp_bf = x_bf + SC;                       // SC
    unsigned short* WT    = xp_bf + SC;                      // 4521984
    // aliases (sequentially dead regions)
    unsigned short* msda_bf = (unsigned short*)logits;       // SC bf16 == S*128 f32 bytes
    unsigned short* hbuf_bf = (unsigned short*)value;        // S*F bf16 == 2*SC f32 bytes

    const unsigned short* WvT = WT + 0;
    const unsigned short* WofT = WT + 393216;
    const unsigned short* WatT = WT + 786432;
    const unsigned short* WouT = WT + 983040;
    const unsigned short* W1T = WT + 1376256;
    const unsigned short* W2T = WT + 2949120;

    prep_weights<<<1104, 256, 0, stream>>>(Wv, Woff, Wattn, Wout, W1, W2, WT);
    prep_x0<<<1360, 256, 0, stream>>>(src, pos, x_bf, xp_bf);

    const float* x = src;   // fp32 residual stream
    for (int i = 0; i < N_LAYERS; ++i) {
        proj_bf<<<dim3(85, 5), 256, 0, stream>>>(
            x_bf, xp_bf,
            WvT + (long)i * 65536, bv + i * C,
            WofT + (long)i * 65536, boff + (long)i * 256,
            WatT + (long)i * 32768, battn + (long)i * 128,
            value, offraw, logits);

        msda_sample<<<S, 256, 0, stream>>>(value, offraw, logits, vr, msda_bf);

        // tmp = msda @ Wout^T + bout + x
        gemm_bf<<<dim3(85, 2), 256, 0, stream>>>(
            msda_bf, WouT + (long)i * 65536, bout + i * C, x, tmp, nullptr, 256, 256, 0);

        // LN1 -> xbuf fp32 + x_bf
        ln4<<<S / 4, 256, 0, stream>>>(tmp, ln1g + i * C, ln1b + i * C, xbuf, x_bf, nullptr, nullptr);

        // hbuf = relu(x @ W1^T + b1)  (bf16 only)
        gemm_bf<<<dim3(85, 8), 256, 0, stream>>>(
            x_bf, W1T + (long)i * 262144, b1 + (long)i * F_DIM, nullptr, nullptr, hbuf_bf, 256, 1024, 1);

        // tmp = hbuf @ W2^T + b2 + xbuf
        gemm_bf<<<dim3(85, 2), 256, 0, stream>>>(
            hbuf_bf, W2T + (long)i * 262144, b2 + i * C, xbuf, tmp, nullptr, 1024, 256, 0);

        // LN2
        float* dst = (i == N_LAYERS - 1) ? (float*)d_out : xbuf;
        if (i == N_LAYERS - 1) {
            ln4<<<S / 4, 256, 0, stream>>>(tmp, ln2g + i * C, ln2b + i * C, dst, nullptr, nullptr, nullptr);
        } else {
            ln4<<<S / 4, 256, 0, stream>>>(tmp, ln2g + i * C, ln2b + i * C, dst, x_bf, pos, xp_bf);
        }
        x = xbuf;
    }
}